// Round 7
// baseline (50.802 us; speedup 1.0000x reference)
//
#include <hip/hip_runtime.h>
#include <math.h>

#define LOG2E 1.4426950408889634f
// s[i,j] = Ci + Dj + sum_h ab_h*|hq_ih + hkb_jh|,  ab = 0.05*a, Dj = 0.075*(a.hkb_j)
// Ci is constant per row -> cancels in softmax -> dropped.

// ---------------- Kernel A: hq = qs@(Wq+Wd); hkbT[b][h][j] = ks@(Wk-Wd)+bias; Dj; abd
__global__ __launch_bounds__(256) void prep_kernel(
    const float* __restrict__ qs, const float* __restrict__ ks,
    const float* __restrict__ W, const float* __restrict__ bias,
    const float* __restrict__ a,
    float* __restrict__ hq, float* __restrict__ hkbT,
    float* __restrict__ Dj, float* __restrict__ abd) {
  __shared__ __align__(16) float wcomb[64][68];
  __shared__ __align__(16) float xin[64][68];
  const int blk = blockIdx.x;
  const bool qpart = blk < 64;
  const int r0 = (qpart ? blk : blk - 64) * 64;
  const int t = threadIdx.x;
  const float* src = qpart ? qs : ks;
  if (blk == 0 && t < 64) abd[t] = 0.05f * a[t];
  for (int rep = 0; rep < 16; ++rep) {
    int e = rep * 256 + t;
    int row = e >> 6, col = e & 63;
    float wd = W[(128 + row) * 64 + col];
    float wm = qpart ? (W[row * 64 + col] + wd)
                     : (W[(64 + row) * 64 + col] - wd);
    wcomb[row][col] = wm;
    xin[row][col] = src[(r0 + row) * 64 + col];
  }
  __syncthreads();
  const int r = t >> 2;
  const int h0 = (t & 3) << 4;
  float acc[16];
#pragma unroll
  for (int k = 0; k < 16; ++k) acc[k] = 0.f;
#pragma unroll 8
  for (int d = 0; d < 64; ++d) {
    float xv = xin[r][d];
#pragma unroll
    for (int c = 0; c < 4; ++c) {
      float4 w4 = *(const float4*)&wcomb[d][h0 + (c << 2)];
      acc[c * 4 + 0] = fmaf(xv, w4.x, acc[c * 4 + 0]);
      acc[c * 4 + 1] = fmaf(xv, w4.y, acc[c * 4 + 1]);
      acc[c * 4 + 2] = fmaf(xv, w4.z, acc[c * 4 + 2]);
      acc[c * 4 + 3] = fmaf(xv, w4.w, acc[c * 4 + 3]);
    }
  }
  int grow = r0 + r;
  if (qpart) {
#pragma unroll
    for (int c = 0; c < 4; ++c) {
      float4 o;
      o.x = acc[c * 4 + 0]; o.y = acc[c * 4 + 1];
      o.z = acc[c * 4 + 2]; o.w = acc[c * 4 + 3];
      *(float4*)&hq[grow * 64 + h0 + (c << 2)] = o;
    }
  } else {
    int bidx = grow >> 10;
    int j = grow & 1023;
    float part = 0.f;
#pragma unroll
    for (int k = 0; k < 16; ++k) {
      float v = acc[k] + bias[h0 + k];
      hkbT[(bidx * 64 + h0 + k) * 1024 + j] = v;
      part += a[h0 + k] * v;
    }
    part += __shfl_xor(part, 1);
    part += __shfl_xor(part, 2);
    if ((t & 3) == 0) Dj[bidx * 1024 + j] = 0.075f * part;
  }
}

// ---------------- Kernel B: 4 rows x 512 j per block (hz split); LDS-broadcast q
__global__ __launch_bounds__(256) void attn7_kernel(
    const float* __restrict__ vs,
    const float* __restrict__ hq, const float* __restrict__ hkbT,
    const float* __restrict__ Dj, const float* __restrict__ abd,
    float* __restrict__ out0, float* __restrict__ opart1,
    float* __restrict__ mpart, float* __restrict__ lpart) {
  __shared__ __align__(16) float plds[4][512];  // 8KB; reused as obuf
  __shared__ __align__(16) float qlds[4 * 64];  // 1KB
  __shared__ __align__(16) float ablds[64];
  __shared__ float redm[4][4];
  __shared__ float redl[4][4];

  const int t = threadIdx.x;
  const int lane = t & 63;
  const int w = t >> 6;
  const int b = blockIdx.y;
  const int rowbase = blockIdx.x * 4;
  const int hz = blockIdx.z;
  const int growbase = b * 1024 + rowbase;

  const float* hkbT_b = hkbT + b * 65536 + hz * 512;
  const float* v_b = vs + (b * 1024 + hz * 512) * 64;

  if (t < 128) *(float2*)&qlds[t * 2] = *(const float2*)(hq + growbase * 64 + t * 2);
  if (t >= 128 && t < 192) ablds[t - 128] = abd[t - 128];
  __syncthreads();

  const int jloc = w * 128 + lane * 2;
  float2 d2 = *(const float2*)(Dj + b * 1024 + hz * 512 + jloc);

  float s[4][2];
#pragma unroll
  for (int r = 0; r < 4; ++r) { s[r][0] = 0.f; s[r][1] = 0.f; }

  // ---- scores: s[r][c] += ab_h * |q[r][h] + k[h][jloc+c]| ----
  // k double-buffered in registers; #pragma unroll 1 bounds liveness.
  float2 kA[4], kB[4];
#pragma unroll
  for (int hh = 0; hh < 4; ++hh) {
    kA[hh] = *(const float2*)(hkbT_b + hh * 1024 + jloc);
    kB[hh] = *(const float2*)(hkbT_b + (4 + hh) * 1024 + jloc);
  }
#pragma unroll 1
  for (int s2 = 0; s2 < 8; ++s2) {
    const int h0 = s2 * 8;
    const int hn = (s2 < 7) ? h0 + 8 : h0;  // last iter: harmless reload
    float2 nA[4], nB[4];
#pragma unroll
    for (int hh = 0; hh < 4; ++hh) {
      nA[hh] = *(const float2*)(hkbT_b + (hn + hh) * 1024 + jloc);
      nB[hh] = *(const float2*)(hkbT_b + (hn + 4 + hh) * 1024 + jloc);
    }
    float avA[4], avB[4];
    *(float4*)avA = *(const float4*)&ablds[h0];
    *(float4*)avB = *(const float4*)&ablds[h0 + 4];
#pragma unroll
    for (int r = 0; r < 4; ++r) {
      float qvA[4], qvB[4];
      *(float4*)qvA = *(const float4*)&qlds[r * 64 + h0];
      *(float4*)qvB = *(const float4*)&qlds[r * 64 + h0 + 4];
#pragma unroll
      for (int hh = 0; hh < 4; ++hh) {
        float x0 = qvA[hh] + kA[hh].x;
        s[r][0] = fmaf(avA[hh], fabsf(x0), s[r][0]);
        float x1 = qvA[hh] + kA[hh].y;
        s[r][1] = fmaf(avA[hh], fabsf(x1), s[r][1]);
        float y0 = qvB[hh] + kB[hh].x;
        s[r][0] = fmaf(avB[hh], fabsf(y0), s[r][0]);
        float y1 = qvB[hh] + kB[hh].y;
        s[r][1] = fmaf(avB[hh], fabsf(y1), s[r][1]);
      }
    }
#pragma unroll
    for (int hh = 0; hh < 4; ++hh) { kA[hh] = nA[hh]; kB[hh] = nB[hh]; }
  }
#pragma unroll
  for (int r = 0; r < 4; ++r) { s[r][0] += d2.x; s[r][1] += d2.y; }

  // ---- partial softmax over this block's 512 j ----
#pragma unroll
  for (int r = 0; r < 4; ++r) {
    float m = fmaxf(s[r][0], s[r][1]);
#pragma unroll
    for (int off = 32; off >= 1; off >>= 1) m = fmaxf(m, __shfl_xor(m, off));
    if (lane == 0) redm[r][w] = m;
  }
  __syncthreads();
  float mx[4];
#pragma unroll
  for (int r = 0; r < 4; ++r) {
    float4 rm = *(const float4*)&redm[r][0];
    mx[r] = fmaxf(fmaxf(rm.x, rm.y), fmaxf(rm.z, rm.w));
  }
#pragma unroll
  for (int r = 0; r < 4; ++r) {
    float p0 = __builtin_amdgcn_exp2f((s[r][0] - mx[r]) * LOG2E);
    float p1 = __builtin_amdgcn_exp2f((s[r][1] - mx[r]) * LOG2E);
    float2 pw; pw.x = p0; pw.y = p1;
    *(float2*)&plds[r][jloc] = pw;
    float ps = p0 + p1;
#pragma unroll
    for (int off = 32; off >= 1; off >>= 1) ps += __shfl_xor(ps, off);
    if (lane == 0) redl[r][w] = ps;
  }
  __syncthreads();
  float lt[4];
#pragma unroll
  for (int r = 0; r < 4; ++r) {
    float4 rl = *(const float4*)&redl[r][0];
    lt[r] = (rl.x + rl.y) + (rl.z + rl.w);
  }
#pragma unroll
  for (int r = 0; r < 4; ++r) {
    if (t == r) {
      mpart[hz * 4096 + growbase + r] = mx[r];
      lpart[hz * 4096 + growbase + r] = lt[r];
    }
  }

  // ---- PV over this wave's own 128-j chunk ----
  const int jsub = lane >> 4;
  const int dq = (lane & 15) * 4;
  const int cbase = w * 128;
  float o[4][4];
#pragma unroll
  for (int r = 0; r < 4; ++r)
#pragma unroll
    for (int dd = 0; dd < 4; ++dd) o[r][dd] = 0.f;

#pragma unroll 2
  for (int step = 0; step < 8; ++step) {
    int j = cbase + step * 16 + jsub * 4;
    float4 v0 = *(const float4*)(v_b + (j + 0) * 64 + dq);
    float4 v1 = *(const float4*)(v_b + (j + 1) * 64 + dq);
    float4 v2 = *(const float4*)(v_b + (j + 2) * 64 + dq);
    float4 v3 = *(const float4*)(v_b + (j + 3) * 64 + dq);
#pragma unroll
    for (int r = 0; r < 4; ++r) {
      float4 p4 = *(const float4*)&plds[r][j];
      o[r][0] = fmaf(p4.x, v0.x, o[r][0]); o[r][1] = fmaf(p4.x, v0.y, o[r][1]);
      o[r][2] = fmaf(p4.x, v0.z, o[r][2]); o[r][3] = fmaf(p4.x, v0.w, o[r][3]);
      o[r][0] = fmaf(p4.y, v1.x, o[r][0]); o[r][1] = fmaf(p4.y, v1.y, o[r][1]);
      o[r][2] = fmaf(p4.y, v1.z, o[r][2]); o[r][3] = fmaf(p4.y, v1.w, o[r][3]);
      o[r][0] = fmaf(p4.z, v2.x, o[r][0]); o[r][1] = fmaf(p4.z, v2.y, o[r][1]);
      o[r][2] = fmaf(p4.z, v2.z, o[r][2]); o[r][3] = fmaf(p4.z, v2.w, o[r][3]);
      o[r][0] = fmaf(p4.w, v3.x, o[r][0]); o[r][1] = fmaf(p4.w, v3.y, o[r][1]);
      o[r][2] = fmaf(p4.w, v3.z, o[r][2]); o[r][3] = fmaf(p4.w, v3.w, o[r][3]);
    }
  }
  __syncthreads();  // all p reads done before obuf reuse

#pragma unroll
  for (int r = 0; r < 4; ++r)
#pragma unroll
    for (int dd = 0; dd < 4; ++dd) {
      o[r][dd] += __shfl_xor(o[r][dd], 16);
      o[r][dd] += __shfl_xor(o[r][dd], 32);
    }
  float* ob = &plds[0][0];  // [4w][4r][64d] = 4KB
  if (lane < 16) {
#pragma unroll
    for (int r = 0; r < 4; ++r) {
      float4 ov; ov.x = o[r][0]; ov.y = o[r][1]; ov.z = o[r][2]; ov.w = o[r][3];
      *(float4*)&ob[(w * 4 + r) * 64 + dq] = ov;
    }
  }
  __syncthreads();
  {
    int r = t >> 6, d = t & 63;
    float ax = 0.f;
#pragma unroll
    for (int wv = 0; wv < 4; ++wv) ax += ob[(wv * 4 + r) * 64 + d];
    float* obase = (hz == 0) ? out0 : opart1;
    obase[(growbase + r) * 64 + d] = ax;  // unnormalized partial
  }
}

// ---------------- Kernel C: combine the two j-halves, normalize in place ------
__global__ __launch_bounds__(256) void combine_kernel(
    const float* __restrict__ opart1, const float* __restrict__ mpart,
    const float* __restrict__ lpart, float* __restrict__ out) {
  int idx = blockIdx.x * 256 + threadIdx.x;
  int e = idx * 2;
  int row = e >> 6;
  float m0 = mpart[row], m1 = mpart[4096 + row];
  float l0 = lpart[row], l1 = lpart[4096 + row];
  float M = fmaxf(m0, m1);
  float w0 = __builtin_amdgcn_exp2f((m0 - M) * LOG2E);
  float w1 = __builtin_amdgcn_exp2f((m1 - M) * LOG2E);
  float inv = 1.f / (l0 * w0 + l1 * w1);
  float2 o0 = *(const float2*)&out[e];
  float2 o1 = *(const float2*)&opart1[e];
  float2 res;
  res.x = (o0.x * w0 + o1.x * w1) * inv;
  res.y = (o0.y * w0 + o1.y * w1) * inv;
  *(float2*)&out[e] = res;
}

extern "C" void kernel_launch(void* const* d_in, const int* in_sizes, int n_in,
                              void* d_out, int out_size, void* d_ws, size_t ws_size,
                              hipStream_t stream) {
  const float* qs = (const float*)d_in[0];
  const float* ks = (const float*)d_in[1];
  const float* vs = (const float*)d_in[2];
  const float* W  = (const float*)d_in[3];
  const float* bi = (const float*)d_in[4];
  const float* a  = (const float*)d_in[5];
  float* out = (float*)d_out;
  float* hq     = (float*)d_ws;             // 1MB
  float* hkbT   = hq + 262144;              // 1MB
  float* Dj     = hkbT + 262144;            // 16KB
  float* abd    = Dj + 4096;                // 256B
  float* opart1 = abd + 64;                 // 1MB
  float* mpart  = opart1 + 262144;          // 32KB
  float* lpart  = mpart + 8192;             // 32KB
  prep_kernel<<<128, 256, 0, stream>>>(qs, ks, W, bi, a, hq, hkbT, Dj, abd);
  attn7_kernel<<<dim3(256, 4, 2), 256, 0, stream>>>(vs, hq, hkbT, Dj, abd,
                                                    out, opart1, mpart, lpart);
  combine_kernel<<<512, 256, 0, stream>>>(opart1, mpart, lpart, out);
}

// Round 9
// 40.537 us; speedup vs baseline: 1.2532x; 1.2532x over previous
//
#include <hip/hip_runtime.h>
#include <math.h>

#define LOG2E 1.4426950408889634f
typedef __attribute__((ext_vector_type(2))) _Float16 h2v;

static __device__ __forceinline__ unsigned pkrtz_u32(float lo, float hi) {
  auto p = __builtin_amdgcn_cvt_pkrtz(lo, hi);  // __fp16 ext_vector(2)
  unsigned u; __builtin_memcpy(&u, &p, 4); return u;
}
static __device__ __forceinline__ h2v habs2(h2v x) {
  unsigned u; __builtin_memcpy(&u, &x, 4);
  u &= 0x7FFF7FFFu;
  h2v r; __builtin_memcpy(&r, &u, 4); return r;
}
static __device__ __forceinline__ h2v u2h(unsigned u) {
  h2v r; __builtin_memcpy(&r, &u, 4); return r;
}

// s[i,j] = Ci + Dj + sum_h ab_h*|hq_ih + hkb_jh|, ab = 0.05*a, Dj = 0.075*(a.hkb_j)
// Ci is per-row constant -> cancels in softmax -> dropped.
// khT4: [b][h4][j] uint4 = f16 pairs of h = 8*h4..8*h4+7 (bias folded in).
// hq2:  [row][h2] u32 f16 pairs.  abd2: [h2] u32 f16 pairs of 0.05*a.

// ---------------- Kernel A ----------------------------------------------------
__global__ __launch_bounds__(256) void prep_kernel(
    const float* __restrict__ qs, const float* __restrict__ ks,
    const float* __restrict__ W, const float* __restrict__ bias,
    const float* __restrict__ a,
    unsigned* __restrict__ hq2, uint4* __restrict__ khT4,
    float* __restrict__ Dj, unsigned* __restrict__ abd2) {
  __shared__ __align__(16) float wcomb[64][68];
  __shared__ __align__(16) float xin[64][68];
  const int blk = blockIdx.x;
  const bool qpart = blk < 64;
  const int r0 = (qpart ? blk : blk - 64) * 64;
  const int t = threadIdx.x;
  const float* src = qpart ? qs : ks;
  if (blk == 0 && t < 32) {
    abd2[t] = pkrtz_u32(0.05f * a[2 * t], 0.05f * a[2 * t + 1]);
  }
  for (int rep = 0; rep < 16; ++rep) {
    int e = rep * 256 + t;
    int row = e >> 6, col = e & 63;
    float wd = W[(128 + row) * 64 + col];
    float wm = qpart ? (W[row * 64 + col] + wd)
                     : (W[(64 + row) * 64 + col] - wd);
    wcomb[row][col] = wm;
    xin[row][col] = src[(r0 + row) * 64 + col];
  }
  __syncthreads();
  const int r = t >> 2;
  const int h0 = (t & 3) << 4;
  float acc[16];
#pragma unroll
  for (int k = 0; k < 16; ++k) acc[k] = 0.f;
#pragma unroll 8
  for (int d = 0; d < 64; ++d) {
    float xv = xin[r][d];
#pragma unroll
    for (int c = 0; c < 4; ++c) {
      float4 w4 = *(const float4*)&wcomb[d][h0 + (c << 2)];
      acc[c * 4 + 0] = fmaf(xv, w4.x, acc[c * 4 + 0]);
      acc[c * 4 + 1] = fmaf(xv, w4.y, acc[c * 4 + 1]);
      acc[c * 4 + 2] = fmaf(xv, w4.z, acc[c * 4 + 2]);
      acc[c * 4 + 3] = fmaf(xv, w4.w, acc[c * 4 + 3]);
    }
  }
  int grow = r0 + r;
  if (qpart) {
    // pack hq to f16 pairs: hq2[grow*32 + (t&3)*8 + i]
    unsigned pr[8];
#pragma unroll
    for (int i = 0; i < 8; ++i) pr[i] = pkrtz_u32(acc[2 * i], acc[2 * i + 1]);
    uint4* dst = (uint4*)&hq2[grow * 32 + (t & 3) * 8];
    dst[0] = make_uint4(pr[0], pr[1], pr[2], pr[3]);
    dst[1] = make_uint4(pr[4], pr[5], pr[6], pr[7]);
  } else {
    int bidx = grow >> 10;
    int j = grow & 1023;
    float val[16];
    float part = 0.f;
#pragma unroll
    for (int k = 0; k < 16; ++k) {
      val[k] = acc[k] + bias[h0 + k];
      part += a[h0 + k] * val[k];
    }
    part += __shfl_xor(part, 1);
    part += __shfl_xor(part, 2);
    if ((t & 3) == 0) Dj[bidx * 1024 + j] = 0.075f * part;
    unsigned pr[8];
#pragma unroll
    for (int i = 0; i < 8; ++i) pr[i] = pkrtz_u32(val[2 * i], val[2 * i + 1]);
    const int h4a = (t & 3) * 2;
    khT4[(bidx * 8 + h4a) * 1024 + j]     = make_uint4(pr[0], pr[1], pr[2], pr[3]);
    khT4[(bidx * 8 + h4a + 1) * 1024 + j] = make_uint4(pr[4], pr[5], pr[6], pr[7]);
  }
}

// ---------------- Kernel B: 4 rows x 512 j per block; f16 dot2 scores ---------
__global__ __launch_bounds__(256) void attn8_kernel(
    const float* __restrict__ vs,
    const unsigned* __restrict__ hq2, const uint4* __restrict__ khT4,
    const float* __restrict__ Dj, const unsigned* __restrict__ abd2,
    float* __restrict__ out0, float* __restrict__ opart1,
    float* __restrict__ mpart, float* __restrict__ lpart) {
  __shared__ __align__(16) float plds[4][512];      // 8KB; reused as obuf
  __shared__ __align__(16) unsigned q2lds[4 * 32];  // 512B
  __shared__ __align__(16) unsigned ab2lds[32];     // 128B
  __shared__ float redm[4][4];
  __shared__ float redl[4][4];

  const int t = threadIdx.x;
  const int lane = t & 63;
  const int w = t >> 6;
  const int b = blockIdx.y;
  const int rowbase = blockIdx.x * 4;
  const int hz = blockIdx.z;
  const int growbase = b * 1024 + rowbase;

  const uint4* kh_b = khT4 + (size_t)b * 8 * 1024 + hz * 512;
  const float* v_b = vs + (b * 1024 + hz * 512) * 64;

  if (t < 128) q2lds[t] = hq2[growbase * 32 + t];
  if (t >= 128 && t < 160) ab2lds[t - 128] = abd2[t - 128];
  __syncthreads();

  const int jloc = w * 128 + lane * 2;
  float2 d2 = *(const float2*)(Dj + b * 1024 + hz * 512 + jloc);

  float s[4][2];
#pragma unroll
  for (int r = 0; r < 4; ++r) { s[r][0] = 0.f; s[r][1] = 0.f; }

  // ---- scores: per h4-group (8 h), k double-buffered ----
  uint4 kc0 = kh_b[jloc], kc1 = kh_b[jloc + 1];
#pragma unroll 1
  for (int it = 0; it < 8; ++it) {
    const int nx = (it < 7) ? it + 1 : it;  // last iter: harmless reload
    uint4 kn0 = kh_b[nx * 1024 + jloc];
    uint4 kn1 = kh_b[nx * 1024 + jloc + 1];
    uint4 abq = *(const uint4*)&ab2lds[it * 4];
    const unsigned abu[4] = {abq.x, abq.y, abq.z, abq.w};
    const unsigned kc0u[4] = {kc0.x, kc0.y, kc0.z, kc0.w};
    const unsigned kc1u[4] = {kc1.x, kc1.y, kc1.z, kc1.w};
#pragma unroll
    for (int r = 0; r < 4; ++r) {
      uint4 qq = *(const uint4*)&q2lds[r * 32 + it * 4];
      const unsigned qu[4] = {qq.x, qq.y, qq.z, qq.w};
#pragma unroll
      for (int u = 0; u < 4; ++u) {
        h2v qh = u2h(qu[u]);
        h2v a2 = u2h(abu[u]);
        h2v x0 = habs2(qh + u2h(kc0u[u]));
        s[r][0] = __builtin_amdgcn_fdot2(a2, x0, s[r][0], false);
        h2v x1 = habs2(qh + u2h(kc1u[u]));
        s[r][1] = __builtin_amdgcn_fdot2(a2, x1, s[r][1], false);
      }
    }
    kc0 = kn0; kc1 = kn1;
  }
#pragma unroll
  for (int r = 0; r < 4; ++r) { s[r][0] += d2.x; s[r][1] += d2.y; }

  // ---- partial softmax over this block's 512 j ----
#pragma unroll
  for (int r = 0; r < 4; ++r) {
    float m = fmaxf(s[r][0], s[r][1]);
#pragma unroll
    for (int off = 32; off >= 1; off >>= 1) m = fmaxf(m, __shfl_xor(m, off));
    if (lane == 0) redm[r][w] = m;
  }
  __syncthreads();
  float mx[4];
#pragma unroll
  for (int r = 0; r < 4; ++r) {
    float4 rm = *(const float4*)&redm[r][0];
    mx[r] = fmaxf(fmaxf(rm.x, rm.y), fmaxf(rm.z, rm.w));
  }
#pragma unroll
  for (int r = 0; r < 4; ++r) {
    float p0 = __builtin_amdgcn_exp2f((s[r][0] - mx[r]) * LOG2E);
    float p1 = __builtin_amdgcn_exp2f((s[r][1] - mx[r]) * LOG2E);
    float2 pw; pw.x = p0; pw.y = p1;
    *(float2*)&plds[r][jloc] = pw;
    float ps = p0 + p1;
#pragma unroll
    for (int off = 32; off >= 1; off >>= 1) ps += __shfl_xor(ps, off);
    if (lane == 0) redl[r][w] = ps;
  }
  __syncthreads();
  float lt[4];
#pragma unroll
  for (int r = 0; r < 4; ++r) {
    float4 rl = *(const float4*)&redl[r][0];
    lt[r] = (rl.x + rl.y) + (rl.z + rl.w);
  }
#pragma unroll
  for (int r = 0; r < 4; ++r) {
    if (t == r) {
      mpart[hz * 4096 + growbase + r] = mx[r];
      lpart[hz * 4096 + growbase + r] = lt[r];
    }
  }

  // ---- PV over this wave's own 128-j chunk ----
  const int jsub = lane >> 4;
  const int dq = (lane & 15) * 4;
  const int cbase = w * 128;
  float o[4][4];
#pragma unroll
  for (int r = 0; r < 4; ++r)
#pragma unroll
    for (int dd = 0; dd < 4; ++dd) o[r][dd] = 0.f;

#pragma unroll 2
  for (int step = 0; step < 8; ++step) {
    int j = cbase + step * 16 + jsub * 4;
    float4 v0 = *(const float4*)(v_b + (j + 0) * 64 + dq);
    float4 v1 = *(const float4*)(v_b + (j + 1) * 64 + dq);
    float4 v2 = *(const float4*)(v_b + (j + 2) * 64 + dq);
    float4 v3 = *(const float4*)(v_b + (j + 3) * 64 + dq);
#pragma unroll
    for (int r = 0; r < 4; ++r) {
      float4 p4 = *(const float4*)&plds[r][j];
      o[r][0] = fmaf(p4.x, v0.x, o[r][0]); o[r][1] = fmaf(p4.x, v0.y, o[r][1]);
      o[r][2] = fmaf(p4.x, v0.z, o[r][2]); o[r][3] = fmaf(p4.x, v0.w, o[r][3]);
      o[r][0] = fmaf(p4.y, v1.x, o[r][0]); o[r][1] = fmaf(p4.y, v1.y, o[r][1]);
      o[r][2] = fmaf(p4.y, v1.z, o[r][2]); o[r][3] = fmaf(p4.y, v1.w, o[r][3]);
      o[r][0] = fmaf(p4.z, v2.x, o[r][0]); o[r][1] = fmaf(p4.z, v2.y, o[r][1]);
      o[r][2] = fmaf(p4.z, v2.z, o[r][2]); o[r][3] = fmaf(p4.z, v2.w, o[r][3]);
      o[r][0] = fmaf(p4.w, v3.x, o[r][0]); o[r][1] = fmaf(p4.w, v3.y, o[r][1]);
      o[r][2] = fmaf(p4.w, v3.z, o[r][2]); o[r][3] = fmaf(p4.w, v3.w, o[r][3]);
    }
  }
  __syncthreads();  // all p reads done before obuf reuse

#pragma unroll
  for (int r = 0; r < 4; ++r)
#pragma unroll
    for (int dd = 0; dd < 4; ++dd) {
      o[r][dd] += __shfl_xor(o[r][dd], 16);
      o[r][dd] += __shfl_xor(o[r][dd], 32);
    }
  float* ob = &plds[0][0];  // [4w][4r][64d] = 4KB
  if (lane < 16) {
#pragma unroll
    for (int r = 0; r < 4; ++r) {
      float4 ov; ov.x = o[r][0]; ov.y = o[r][1]; ov.z = o[r][2]; ov.w = o[r][3];
      *(float4*)&ob[(w * 4 + r) * 64 + dq] = ov;
    }
  }
  __syncthreads();
  {
    int r = t >> 6, d = t & 63;
    float ax = 0.f;
#pragma unroll
    for (int wv = 0; wv < 4; ++wv) ax += ob[(wv * 4 + r) * 64 + d];
    float* obase = (hz == 0) ? out0 : opart1;
    obase[(growbase + r) * 64 + d] = ax;  // unnormalized partial
  }
}

// ---------------- Kernel C: combine the two j-halves, normalize in place ------
__global__ __launch_bounds__(256) void combine_kernel(
    const float* __restrict__ opart1, const float* __restrict__ mpart,
    const float* __restrict__ lpart, float* __restrict__ out) {
  int idx = blockIdx.x * 256 + threadIdx.x;
  int e = idx * 2;
  int row = e >> 6;
  float m0 = mpart[row], m1 = mpart[4096 + row];
  float l0 = lpart[row], l1 = lpart[4096 + row];
  float M = fmaxf(m0, m1);
  float w0 = __builtin_amdgcn_exp2f((m0 - M) * LOG2E);
  float w1 = __builtin_amdgcn_exp2f((m1 - M) * LOG2E);
  float inv = 1.f / (l0 * w0 + l1 * w1);
  float2 o0 = *(const float2*)&out[e];
  float2 o1 = *(const float2*)&opart1[e];
  float2 res;
  res.x = (o0.x * w0 + o1.x * w1) * inv;
  res.y = (o0.y * w0 + o1.y * w1) * inv;
  *(float2*)&out[e] = res;
}

extern "C" void kernel_launch(void* const* d_in, const int* in_sizes, int n_in,
                              void* d_out, int out_size, void* d_ws, size_t ws_size,
                              hipStream_t stream) {
  const float* qs = (const float*)d_in[0];
  const float* ks = (const float*)d_in[1];
  const float* vs = (const float*)d_in[2];
  const float* W  = (const float*)d_in[3];
  const float* bi = (const float*)d_in[4];
  const float* a  = (const float*)d_in[5];
  float* out = (float*)d_out;
  unsigned* hq2   = (unsigned*)d_ws;              // 4096*32 u32 = 512KB
  uint4*    khT4  = (uint4*)((char*)d_ws + 524288);  // 4*8*1024*16B = 512KB
  float*    Dj    = (float*)((char*)d_ws + 1048576); // 16KB
  unsigned* abd2  = (unsigned*)((char*)d_ws + 1064960); // 128B
  float*    opart1= (float*)((char*)d_ws + 1065216);    // 1MB
  float*    mpart = (float*)((char*)d_ws + 2113792);    // 32KB
  float*    lpart = (float*)((char*)d_ws + 2146560);    // 32KB
  prep_kernel<<<128, 256, 0, stream>>>(qs, ks, W, bi, a, hq2, khT4, Dj, abd2);
  attn8_kernel<<<dim3(256, 4, 2), 256, 0, stream>>>(vs, hq2, khT4, Dj, abd2,
                                                    out, opart1, mpart, lpart);
  combine_kernel<<<512, 256, 0, stream>>>(opart1, mpart, lpart, out);
}

// Round 10
// 37.305 us; speedup vs baseline: 1.3618x; 1.0866x over previous
//
#include <hip/hip_runtime.h>
#include <math.h>

#define LOG2E 1.4426950408889634f
typedef __attribute__((ext_vector_type(2))) _Float16 h2v;

static __device__ __forceinline__ unsigned pkrtz_u32(float lo, float hi) {
  auto p = __builtin_amdgcn_cvt_pkrtz(lo, hi);  // __fp16 ext_vector(2)
  unsigned u; __builtin_memcpy(&u, &p, 4); return u;
}
static __device__ __forceinline__ h2v habs2(h2v x) {
  unsigned u; __builtin_memcpy(&u, &x, 4);
  u &= 0x7FFF7FFFu;
  h2v r; __builtin_memcpy(&r, &u, 4); return r;
}
static __device__ __forceinline__ h2v u2h(unsigned u) {
  h2v r; __builtin_memcpy(&r, &u, 4); return r;
}

// s[i,j] = Ci + Dj + sum_h ab_h*|hq_ih + hkb_jh|, ab = 0.05*a, Dj = 0.075*(a.hkb_j)
// Ci is per-row constant -> cancels in softmax -> dropped.
// khT4: [b][h4][j] uint4 = f16 pairs of h = 8*h4..8*h4+7 (bias folded in).
// hq2:  [row][h2] u32 f16 pairs.  abd2: [h2] u32 f16 pairs of 0.05*a.

// ---------------- Kernel A ----------------------------------------------------
__global__ __launch_bounds__(256) void prep_kernel(
    const float* __restrict__ qs, const float* __restrict__ ks,
    const float* __restrict__ W, const float* __restrict__ bias,
    const float* __restrict__ a,
    unsigned* __restrict__ hq2, uint4* __restrict__ khT4,
    float* __restrict__ Dj, unsigned* __restrict__ abd2) {
  __shared__ __align__(16) float wcomb[64][68];
  __shared__ __align__(16) float xin[64][68];
  const int blk = blockIdx.x;
  const bool qpart = blk < 64;
  const int r0 = (qpart ? blk : blk - 64) * 64;
  const int t = threadIdx.x;
  const float* src = qpart ? qs : ks;
  if (blk == 0 && t < 32) {
    abd2[t] = pkrtz_u32(0.05f * a[2 * t], 0.05f * a[2 * t + 1]);
  }
  for (int rep = 0; rep < 16; ++rep) {
    int e = rep * 256 + t;
    int row = e >> 6, col = e & 63;
    float wd = W[(128 + row) * 64 + col];
    float wm = qpart ? (W[row * 64 + col] + wd)
                     : (W[(64 + row) * 64 + col] - wd);
    wcomb[row][col] = wm;
    xin[row][col] = src[(r0 + row) * 64 + col];
  }
  __syncthreads();
  const int r = t >> 2;
  const int h0 = (t & 3) << 4;
  float acc[16];
#pragma unroll
  for (int k = 0; k < 16; ++k) acc[k] = 0.f;
#pragma unroll 8
  for (int d = 0; d < 64; ++d) {
    float xv = xin[r][d];
#pragma unroll
    for (int c = 0; c < 4; ++c) {
      float4 w4 = *(const float4*)&wcomb[d][h0 + (c << 2)];
      acc[c * 4 + 0] = fmaf(xv, w4.x, acc[c * 4 + 0]);
      acc[c * 4 + 1] = fmaf(xv, w4.y, acc[c * 4 + 1]);
      acc[c * 4 + 2] = fmaf(xv, w4.z, acc[c * 4 + 2]);
      acc[c * 4 + 3] = fmaf(xv, w4.w, acc[c * 4 + 3]);
    }
  }
  int grow = r0 + r;
  if (qpart) {
    unsigned pr[8];
#pragma unroll
    for (int i = 0; i < 8; ++i) pr[i] = pkrtz_u32(acc[2 * i], acc[2 * i + 1]);
    uint4* dst = (uint4*)&hq2[grow * 32 + (t & 3) * 8];
    dst[0] = make_uint4(pr[0], pr[1], pr[2], pr[3]);
    dst[1] = make_uint4(pr[4], pr[5], pr[6], pr[7]);
  } else {
    int bidx = grow >> 10;
    int j = grow & 1023;
    float val[16];
    float part = 0.f;
#pragma unroll
    for (int k = 0; k < 16; ++k) {
      val[k] = acc[k] + bias[h0 + k];
      part += a[h0 + k] * val[k];
    }
    part += __shfl_xor(part, 1);
    part += __shfl_xor(part, 2);
    if ((t & 3) == 0) Dj[bidx * 1024 + j] = 0.075f * part;
    unsigned pr[8];
#pragma unroll
    for (int i = 0; i < 8; ++i) pr[i] = pkrtz_u32(val[2 * i], val[2 * i + 1]);
    const int h4a = (t & 3) * 2;
    khT4[(bidx * 8 + h4a) * 1024 + j]     = make_uint4(pr[0], pr[1], pr[2], pr[3]);
    khT4[(bidx * 8 + h4a + 1) * 1024 + j] = make_uint4(pr[4], pr[5], pr[6], pr[7]);
  }
}

// ---------------- Kernel B: 4 rows x 1024 j per block; exact softmax; fused out
__global__ __launch_bounds__(256) void attn10_kernel(
    const float* __restrict__ vs,
    const unsigned* __restrict__ hq2, const uint4* __restrict__ khT4,
    const float* __restrict__ Dj, const unsigned* __restrict__ abd2,
    float* __restrict__ out) {
  __shared__ __align__(16) float plds[4][1024];     // 16KB; reused as obuf
  __shared__ __align__(16) unsigned q2lds[4 * 32];  // 512B
  __shared__ __align__(16) unsigned ab2lds[32];     // 128B
  __shared__ float redm[4][4];
  __shared__ float redl[4][4];

  const int t = threadIdx.x;
  const int lane = t & 63;
  const int w = t >> 6;
  const int b = blockIdx.y;
  const int rowbase = blockIdx.x * 4;
  const int growbase = b * 1024 + rowbase;

  const uint4* kh_b = khT4 + (size_t)b * 8 * 1024;
  const float* v_b = vs + b * 1024 * 64;

  if (t < 128) q2lds[t] = hq2[growbase * 32 + t];
  if (t >= 128 && t < 160) ab2lds[t - 128] = abd2[t - 128];
  __syncthreads();

  const int jloc = w * 256 + lane * 4;  // lane owns j = jloc..jloc+3
  float4 d4 = *(const float4*)(Dj + b * 1024 + jloc);

  float s[4][4];
#pragma unroll
  for (int r = 0; r < 4; ++r)
#pragma unroll
    for (int c = 0; c < 4; ++c) s[r][c] = 0.f;

  // ---- scores: per h4-group (8 h), k double-buffered in regs ----
  uint4 kc0 = kh_b[jloc], kc1 = kh_b[jloc + 1], kc2 = kh_b[jloc + 2],
        kc3 = kh_b[jloc + 3];
#pragma unroll 1
  for (int it = 0; it < 8; ++it) {
    const int nx = (it < 7) ? it + 1 : it;  // last iter: harmless reload
    uint4 kn0 = kh_b[nx * 1024 + jloc];
    uint4 kn1 = kh_b[nx * 1024 + jloc + 1];
    uint4 kn2 = kh_b[nx * 1024 + jloc + 2];
    uint4 kn3 = kh_b[nx * 1024 + jloc + 3];
    uint4 abq = *(const uint4*)&ab2lds[it * 4];
    const unsigned abu[4] = {abq.x, abq.y, abq.z, abq.w};
    const unsigned kcu[4][4] = {{kc0.x, kc0.y, kc0.z, kc0.w},
                                {kc1.x, kc1.y, kc1.z, kc1.w},
                                {kc2.x, kc2.y, kc2.z, kc2.w},
                                {kc3.x, kc3.y, kc3.z, kc3.w}};
#pragma unroll
    for (int r = 0; r < 4; ++r) {
      uint4 qq = *(const uint4*)&q2lds[r * 32 + it * 4];
      const unsigned qu[4] = {qq.x, qq.y, qq.z, qq.w};
#pragma unroll
      for (int u = 0; u < 4; ++u) {
        h2v qh = u2h(qu[u]);
        h2v a2 = u2h(abu[u]);
#pragma unroll
        for (int c = 0; c < 4; ++c) {
          h2v x = habs2(qh + u2h(kcu[c][u]));
          s[r][c] = __builtin_amdgcn_fdot2(a2, x, s[r][c], false);
        }
      }
    }
    kc0 = kn0; kc1 = kn1; kc2 = kn2; kc3 = kn3;
  }
#pragma unroll
  for (int r = 0; r < 4; ++r) {
    s[r][0] += d4.x; s[r][1] += d4.y; s[r][2] += d4.z; s[r][3] += d4.w;
  }

  // ---- exact softmax over 1024 j (cross-lane + cross-wave) ----
#pragma unroll
  for (int r = 0; r < 4; ++r) {
    float m = fmaxf(fmaxf(s[r][0], s[r][1]), fmaxf(s[r][2], s[r][3]));
#pragma unroll
    for (int off = 32; off >= 1; off >>= 1) m = fmaxf(m, __shfl_xor(m, off));
    if (lane == 0) redm[r][w] = m;
  }
  __syncthreads();
  float mx[4];
#pragma unroll
  for (int r = 0; r < 4; ++r) {
    float4 rm = *(const float4*)&redm[r][0];
    mx[r] = fmaxf(fmaxf(rm.x, rm.y), fmaxf(rm.z, rm.w));
  }
#pragma unroll
  for (int r = 0; r < 4; ++r) {
    float p0 = __builtin_amdgcn_exp2f((s[r][0] - mx[r]) * LOG2E);
    float p1 = __builtin_amdgcn_exp2f((s[r][1] - mx[r]) * LOG2E);
    float p2 = __builtin_amdgcn_exp2f((s[r][2] - mx[r]) * LOG2E);
    float p3 = __builtin_amdgcn_exp2f((s[r][3] - mx[r]) * LOG2E);
    float4 pw; pw.x = p0; pw.y = p1; pw.z = p2; pw.w = p3;
    *(float4*)&plds[r][jloc] = pw;
    float ps = (p0 + p1) + (p2 + p3);
#pragma unroll
    for (int off = 32; off >= 1; off >>= 1) ps += __shfl_xor(ps, off);
    if (lane == 0) redl[r][w] = ps;
  }
  __syncthreads();

  // ---- PV over this wave's own 256-j chunk ----
  const int jsub = lane >> 4;
  const int dq = (lane & 15) * 4;
  const int cbase = w * 256;
  float o[4][4];
#pragma unroll
  for (int r = 0; r < 4; ++r)
#pragma unroll
    for (int dd = 0; dd < 4; ++dd) o[r][dd] = 0.f;

#pragma unroll 2
  for (int step = 0; step < 16; ++step) {
    int j = cbase + step * 16 + jsub * 4;
    float4 v0 = *(const float4*)(v_b + (j + 0) * 64 + dq);
    float4 v1 = *(const float4*)(v_b + (j + 1) * 64 + dq);
    float4 v2 = *(const float4*)(v_b + (j + 2) * 64 + dq);
    float4 v3 = *(const float4*)(v_b + (j + 3) * 64 + dq);
#pragma unroll
    for (int r = 0; r < 4; ++r) {
      float4 p4 = *(const float4*)&plds[r][j];
      o[r][0] = fmaf(p4.x, v0.x, o[r][0]); o[r][1] = fmaf(p4.x, v0.y, o[r][1]);
      o[r][2] = fmaf(p4.x, v0.z, o[r][2]); o[r][3] = fmaf(p4.x, v0.w, o[r][3]);
      o[r][0] = fmaf(p4.y, v1.x, o[r][0]); o[r][1] = fmaf(p4.y, v1.y, o[r][1]);
      o[r][2] = fmaf(p4.y, v1.z, o[r][2]); o[r][3] = fmaf(p4.y, v1.w, o[r][3]);
      o[r][0] = fmaf(p4.z, v2.x, o[r][0]); o[r][1] = fmaf(p4.z, v2.y, o[r][1]);
      o[r][2] = fmaf(p4.z, v2.z, o[r][2]); o[r][3] = fmaf(p4.z, v2.w, o[r][3]);
      o[r][0] = fmaf(p4.w, v3.x, o[r][0]); o[r][1] = fmaf(p4.w, v3.y, o[r][1]);
      o[r][2] = fmaf(p4.w, v3.z, o[r][2]); o[r][3] = fmaf(p4.w, v3.w, o[r][3]);
    }
  }
  __syncthreads();  // all p reads done before obuf reuse

#pragma unroll
  for (int r = 0; r < 4; ++r)
#pragma unroll
    for (int dd = 0; dd < 4; ++dd) {
      o[r][dd] += __shfl_xor(o[r][dd], 16);
      o[r][dd] += __shfl_xor(o[r][dd], 32);
    }
  float* ob = &plds[0][0];  // [4w][4r][64d] = 4KB
  if (lane < 16) {
#pragma unroll
    for (int r = 0; r < 4; ++r) {
      float4 ov; ov.x = o[r][0]; ov.y = o[r][1]; ov.z = o[r][2]; ov.w = o[r][3];
      *(float4*)&ob[(w * 4 + r) * 64 + dq] = ov;
    }
  }
  __syncthreads();
  {
    int r = t >> 6, d = t & 63;  // r == w (wave-uniform)
    float ax = 0.f;
#pragma unroll
    for (int wv = 0; wv < 4; ++wv) ax += ob[(wv * 4 + r) * 64 + d];
    float4 rl = *(const float4*)&redl[r][0];
    float inv = 1.f / ((rl.x + rl.y) + (rl.z + rl.w));
    out[(growbase + r) * 64 + d] = ax * inv;
  }
}

extern "C" void kernel_launch(void* const* d_in, const int* in_sizes, int n_in,
                              void* d_out, int out_size, void* d_ws, size_t ws_size,
                              hipStream_t stream) {
  const float* qs = (const float*)d_in[0];
  const float* ks = (const float*)d_in[1];
  const float* vs = (const float*)d_in[2];
  const float* W  = (const float*)d_in[3];
  const float* bi = (const float*)d_in[4];
  const float* a  = (const float*)d_in[5];
  float* out = (float*)d_out;
  unsigned* hq2   = (unsigned*)d_ws;                    // 512KB
  uint4*    khT4  = (uint4*)((char*)d_ws + 524288);     // 512KB
  float*    Dj    = (float*)((char*)d_ws + 1048576);    // 16KB
  unsigned* abd2  = (unsigned*)((char*)d_ws + 1064960); // 128B
  prep_kernel<<<128, 256, 0, stream>>>(qs, ks, W, bi, a, hq2, khT4, Dj, abd2);
  attn10_kernel<<<dim3(256, 4), 256, 0, stream>>>(vs, hq2, khT4, Dj, abd2, out);
}